// Round 14
// baseline (106.965 us; speedup 1.0000x reference)
//
#include <hip/hip_runtime.h>

#define EPSV 1e-5f

typedef __fp16 f16x8 __attribute__((ext_vector_type(8)));
typedef float f32x4 __attribute__((ext_vector_type(4)));
typedef __fp16 half2v __attribute__((ext_vector_type(2)));

__device__ __forceinline__ unsigned h2_as_u32(half2v h) {
    union { half2v h; unsigned u; } cv;
    cv.h = h;
    return cv.u;
}

#define LROWS 76
#define LSTRH 88    // halves per row (176B): reads/writes already 8 dw/bank (HW min)
#define LSTR32 44   // u32 per row

// ---------------------------------------------------------------------------
// Kernel 1: fold the 3 branches into one 13x13 kernel + bias; emit per-channel
// MFMA B-fragments: for each dy, 32x16 banded Toeplitz B_dy[k][i] = w[dy][k-i-2]
// in v_mfma_f32_16x16x32_f16 B-fragment order (lane l: i=l&15, k=8*(l>>4)+j).
// ---------------------------------------------------------------------------
__global__ __launch_bounds__(256) void fuse_weights(
    const float* __restrict__ w_large, const float* __restrict__ w_small,
    const float* __restrict__ g_l, const float* __restrict__ b_l,
    const float* __restrict__ m_l, const float* __restrict__ v_l,
    const float* __restrict__ g_s, const float* __restrict__ b_s,
    const float* __restrict__ m_s, const float* __restrict__ v_s,
    const float* __restrict__ g_i, const float* __restrict__ b_i,
    const float* __restrict__ m_i, const float* __restrict__ v_i,
    float* __restrict__ bf, uint4* __restrict__ wB) {
    __shared__ float sw[169];
    const int c = blockIdx.x;
    const int t = threadIdx.x;
    const float sl = g_l[c] * rsqrtf(v_l[c] + EPSV);
    const float ss = g_s[c] * rsqrtf(v_s[c] + EPSV);
    const float si = g_i[c] * rsqrtf(v_i[c] + EPSV);
    if (t < 169) {
        const int ky = t / 13, kx = t % 13;
        float w = w_large[c * 169 + t] * sl;
        if (ky >= 5 && ky <= 7 && kx >= 5 && kx <= 7)
            w += w_small[c * 9 + (ky - 5) * 3 + (kx - 5)] * ss;
        if (t == 6 * 13 + 6) w += si;
        sw[t] = w;
    }
    if (t == 0)
        bf[c] = (b_l[c] - m_l[c] * sl) + (b_s[c] - m_s[c] * ss) +
                (b_i[c] - m_i[c] * si);
    __syncthreads();
    for (int it = t; it < 832; it += 256) {   // 13 dy * 64 lanes
        const int dy = it >> 6;
        const int l = it & 63;
        const int i = l & 15;
        const int kb = (l >> 4) * 8;
        unsigned u[4];
#pragma unroll
        for (int jj = 0; jj < 4; ++jj) {
            const int kx0 = kb + 2 * jj - i - 2;
            const int kx1 = kx0 + 1;
            const float w0 =
                (kx0 >= 0 && kx0 <= 12) ? sw[dy * 13 + kx0] : 0.0f;
            const float w1 =
                (kx1 >= 0 && kx1 <= 12) ? sw[dy * 13 + kx1] : 0.0f;
            u[jj] = h2_as_u32(__builtin_amdgcn_cvt_pkrtz(w0, w1));
        }
        wB[(size_t)c * 832 + it] = make_uint4(u[0], u[1], u[2], u[3]);
    }
}

// ---------------------------------------------------------------------------
// Kernel 2: depthwise 13x13 + bias on matrix cores. One block (4 waves) per
// (n,c) image — R10 structure (best measured) with the register diet:
// the dy loop is split into two phases (dy 0..6 / 7..12) so only SEVEN
// B-fragments are live at once (28 VGPR vs 52); phase-2 fragments are loaded
// between phases (2 global loads per block, L2-hot), pinned by
// sched_barrier(0) so the allocator cannot hoist them. Halo-only zeroing,
// single barrier, x-loads issued first.
// ---------------------------------------------------------------------------
__global__ __launch_bounds__(256, 6) void dwconv_mfma(
    const float* __restrict__ x, const uint4* __restrict__ wB,
    const float* __restrict__ bf, float* __restrict__ out) {
    __shared__ __align__(16) unsigned lds[LROWS * LSTR32];
    __fp16* tile = (__fp16*)lds;

    const int t = threadIdx.x;
    const int img = blockIdx.x;              // n*384 + c
    const int c = __builtin_amdgcn_readfirstlane(img % 384);
    const size_t base = (size_t)img * 4096;

    // ---- issue staging global loads FIRST ----
    const int sr = t >> 2;                   // 0..63
    const int sq = t & 3;                    // 0..3
    const float4* srcp = (const float4*)(x + base + sr * 64 + sq * 16);
    const float4 xr0 = srcp[0];
    const float4 xr1 = srcp[1];
    const float4 xr2 = srcp[2];
    const float4 xr3 = srcp[3];

    // ---- zero halos (disjoint from interior writes; no barrier needed) ----
    // top rows 0..5 / bottom rows 70..75: 11 uint4 per row
    if (t < 132) {
        const int r = t / 11;
        const int rr = (r < 6) ? r : r + 64;
        const int qq = t - r * 11;
        *(uint4*)(lds + rr * LSTR32 + qq * 4) = make_uint4(0u, 0u, 0u, 0u);
    }
    // interior rows 6..69: left halo u32 0..3, right halo u32 36..43
    if (t < 192) {
        const int r = 6 + t / 3;
        const int s = t % 3;
        const int sb = (s == 0) ? 0 : (s == 1 ? 36 : 40);
        *(uint4*)(lds + r * LSTR32 + sb) = make_uint4(0u, 0u, 0u, 0u);
    }

    // ---- stage interior: row R=sr+6, halves [8+16q, 24+16q) ----
    {
        const int R = sr + 6;
        unsigned u[8];
        u[0] = h2_as_u32(__builtin_amdgcn_cvt_pkrtz(xr0.x, xr0.y));
        u[1] = h2_as_u32(__builtin_amdgcn_cvt_pkrtz(xr0.z, xr0.w));
        u[2] = h2_as_u32(__builtin_amdgcn_cvt_pkrtz(xr1.x, xr1.y));
        u[3] = h2_as_u32(__builtin_amdgcn_cvt_pkrtz(xr1.z, xr1.w));
        u[4] = h2_as_u32(__builtin_amdgcn_cvt_pkrtz(xr2.x, xr2.y));
        u[5] = h2_as_u32(__builtin_amdgcn_cvt_pkrtz(xr2.z, xr2.w));
        u[6] = h2_as_u32(__builtin_amdgcn_cvt_pkrtz(xr3.x, xr3.y));
        u[7] = h2_as_u32(__builtin_amdgcn_cvt_pkrtz(xr3.z, xr3.w));
        unsigned* dst = lds + R * LSTR32 + 4 + sq * 8;
        *(uint4*)dst = make_uint4(u[0], u[1], u[2], u[3]);
        *(uint4*)(dst + 4) = make_uint4(u[4], u[5], u[6], u[7]);
    }

    // ---- per-block invariants ----
    const int l = t & 63;
    const int wv = t >> 6;                   // wave id -> col tile c0 = 16*wv
    const uint4* __restrict__ wbp = wB + (size_t)c * 832 + l;
    const float bv = bf[c];

    // phase-1 B-fragments (dy 0..6)
    f16x8 Bf[7];
#pragma unroll
    for (int dy = 0; dy < 7; ++dy) {
        union { uint4 u; f16x8 h; } cv;
        cv.u = wbp[dy * 64];
        Bf[dy] = cv.h;
    }

    __syncthreads();

    const int lrow = l & 15;
    const int kb = (l >> 4) * 8;
    const __fp16* abase = tile + lrow * LSTRH + 16 * wv + kb;

    f32x4 acc0 = {bv, bv, bv, bv};
    f32x4 acc1 = {bv, bv, bv, bv};
    f32x4 acc2 = {bv, bv, bv, bv};
    f32x4 acc3 = {bv, bv, bv, bv};

#pragma unroll
    for (int dy = 0; dy < 7; ++dy) {
        const f16x8 a0 = *(const f16x8*)(abase + (dy) * LSTRH);
        const f16x8 a1 = *(const f16x8*)(abase + (16 + dy) * LSTRH);
        const f16x8 a2 = *(const f16x8*)(abase + (32 + dy) * LSTRH);
        const f16x8 a3 = *(const f16x8*)(abase + (48 + dy) * LSTRH);
        acc0 = __builtin_amdgcn_mfma_f32_16x16x32_f16(a0, Bf[dy], acc0, 0, 0, 0);
        acc1 = __builtin_amdgcn_mfma_f32_16x16x32_f16(a1, Bf[dy], acc1, 0, 0, 0);
        acc2 = __builtin_amdgcn_mfma_f32_16x16x32_f16(a2, Bf[dy], acc2, 0, 0, 0);
        acc3 = __builtin_amdgcn_mfma_f32_16x16x32_f16(a3, Bf[dy], acc3, 0, 0, 0);
    }

    // pin phase-2 fragment loads AFTER phase 1 (keeps only 7 Bf live)
    __builtin_amdgcn_sched_barrier(0);
#pragma unroll
    for (int i = 0; i < 6; ++i) {
        union { uint4 u; f16x8 h; } cv;
        cv.u = wbp[(7 + i) * 64];
        Bf[i] = cv.h;
    }

#pragma unroll
    for (int i = 0; i < 6; ++i) {
        const int dy = 7 + i;
        const f16x8 a0 = *(const f16x8*)(abase + (dy) * LSTRH);
        const f16x8 a1 = *(const f16x8*)(abase + (16 + dy) * LSTRH);
        const f16x8 a2 = *(const f16x8*)(abase + (32 + dy) * LSTRH);
        const f16x8 a3 = *(const f16x8*)(abase + (48 + dy) * LSTRH);
        acc0 = __builtin_amdgcn_mfma_f32_16x16x32_f16(a0, Bf[i], acc0, 0, 0, 0);
        acc1 = __builtin_amdgcn_mfma_f32_16x16x32_f16(a1, Bf[i], acc1, 0, 0, 0);
        acc2 = __builtin_amdgcn_mfma_f32_16x16x32_f16(a2, Bf[i], acc2, 0, 0, 0);
        acc3 = __builtin_amdgcn_mfma_f32_16x16x32_f16(a3, Bf[i], acc3, 0, 0, 0);
    }

    // C layout: col = 16*wv + (l&15), rows = 16*rt + 4*(l>>4) + q
    const int ocol = 16 * wv + (l & 15);
    const int orow = 4 * (l >> 4);
    float* ob = out + base;
#pragma unroll
    for (int q = 0; q < 4; ++q) {
        ob[(orow + q) * 64 + ocol] = acc0[q];
        ob[(16 + orow + q) * 64 + ocol] = acc1[q];
        ob[(32 + orow + q) * 64 + ocol] = acc2[q];
        ob[(48 + orow + q) * 64 + ocol] = acc3[q];
    }
}

// ---------------------------------------------------------------------------
extern "C" void kernel_launch(void* const* d_in, const int* in_sizes, int n_in,
                              void* d_out, int out_size, void* d_ws,
                              size_t ws_size, hipStream_t stream) {
    const float* x = (const float*)d_in[0];
    const float* w_large = (const float*)d_in[1];
    const float* w_small = (const float*)d_in[2];
    const float* g_l = (const float*)d_in[3];
    const float* b_l = (const float*)d_in[4];
    const float* m_l = (const float*)d_in[5];
    const float* v_l = (const float*)d_in[6];
    const float* g_s = (const float*)d_in[7];
    const float* b_s = (const float*)d_in[8];
    const float* m_s = (const float*)d_in[9];
    const float* v_s = (const float*)d_in[10];
    const float* g_i = (const float*)d_in[11];
    const float* b_i = (const float*)d_in[12];
    const float* m_i = (const float*)d_in[13];
    const float* v_i = (const float*)d_in[14];
    float* outp = (float*)d_out;

    // ws layout: bf[384] f32 | wB[384*832] uint4 (5.11 MB)
    float* bfp = (float*)d_ws;
    uint4* wB = (uint4*)(bfp + 384);

    fuse_weights<<<384, 256, 0, stream>>>(w_large, w_small, g_l, b_l, m_l, v_l,
                                          g_s, b_s, m_s, v_s, g_i, b_i, m_i,
                                          v_i, bfp, wB);
    dwconv_mfma<<<16 * 384, 256, 0, stream>>>(x, wB, bfp, outp);
}

// Round 15
// 45.790 us; speedup vs baseline: 2.3360x; 2.3360x over previous
//
#include <hip/hip_runtime.h>

#define EPSV 1e-5f

typedef __fp16 f16x8 __attribute__((ext_vector_type(8)));
typedef float f32x4 __attribute__((ext_vector_type(4)));
typedef __fp16 half2v __attribute__((ext_vector_type(2)));

__device__ __forceinline__ unsigned h2_as_u32(half2v h) {
    union { half2v h; unsigned u; } cv;
    cv.h = h;
    return cv.u;
}

#define LROWS 76
#define LSTRH 88    // halves per row (176B); wave64 b128 = 8 dw/bank (HW min)
#define LSTR32 44   // u32 per row

// ---------------------------------------------------------------------------
// Kernel 1: fold the 3 branches into one 13x13 kernel + bias; emit per-channel
// MFMA B-fragments: for each dy, 32x16 banded Toeplitz B_dy[k][i] = w[dy][k-i-2]
// in v_mfma_f32_16x16x32_f16 B-fragment order (lane l: i=l&15, k=8*(l>>4)+j).
// ---------------------------------------------------------------------------
__global__ __launch_bounds__(256) void fuse_weights(
    const float* __restrict__ w_large, const float* __restrict__ w_small,
    const float* __restrict__ g_l, const float* __restrict__ b_l,
    const float* __restrict__ m_l, const float* __restrict__ v_l,
    const float* __restrict__ g_s, const float* __restrict__ b_s,
    const float* __restrict__ m_s, const float* __restrict__ v_s,
    const float* __restrict__ g_i, const float* __restrict__ b_i,
    const float* __restrict__ m_i, const float* __restrict__ v_i,
    float* __restrict__ bf, uint4* __restrict__ wB) {
    __shared__ float sw[169];
    const int c = blockIdx.x;
    const int t = threadIdx.x;
    const float sl = g_l[c] * rsqrtf(v_l[c] + EPSV);
    const float ss = g_s[c] * rsqrtf(v_s[c] + EPSV);
    const float si = g_i[c] * rsqrtf(v_i[c] + EPSV);
    if (t < 169) {
        const int ky = t / 13, kx = t % 13;
        float w = w_large[c * 169 + t] * sl;
        if (ky >= 5 && ky <= 7 && kx >= 5 && kx <= 7)
            w += w_small[c * 9 + (ky - 5) * 3 + (kx - 5)] * ss;
        if (t == 6 * 13 + 6) w += si;
        sw[t] = w;
    }
    if (t == 0)
        bf[c] = (b_l[c] - m_l[c] * sl) + (b_s[c] - m_s[c] * ss) +
                (b_i[c] - m_i[c] * si);
    __syncthreads();
    for (int it = t; it < 832; it += 256) {   // 13 dy * 64 lanes
        const int dy = it >> 6;
        const int l = it & 63;
        const int i = l & 15;
        const int kb = (l >> 4) * 8;
        unsigned u[4];
#pragma unroll
        for (int jj = 0; jj < 4; ++jj) {
            const int kx0 = kb + 2 * jj - i - 2;
            const int kx1 = kx0 + 1;
            const float w0 =
                (kx0 >= 0 && kx0 <= 12) ? sw[dy * 13 + kx0] : 0.0f;
            const float w1 =
                (kx1 >= 0 && kx1 <= 12) ? sw[dy * 13 + kx1] : 0.0f;
            u[jj] = h2_as_u32(__builtin_amdgcn_cvt_pkrtz(w0, w1));
        }
        wB[(size_t)c * 832 + it] = make_uint4(u[0], u[1], u[2], u[3]);
    }
}

// ---------------------------------------------------------------------------
// Kernel 2: depthwise 13x13 + bias on matrix cores. R10 algorithm, but
// 512 threads = 8 WAVES per block: wave wv owns (col-tile ct=wv&3,
// row-half rh=wv>>2). Per wave: 13 dy x {2 ds_read_b128 + 2 MFMA}, acc = 8
// regs, Bf = 52 regs fully resident -> ~80 regs total, 3 blocks/CU =
// 6 waves/SIMD (vs R10's 4). No forced reg windows, no in-loop global loads.
// ---------------------------------------------------------------------------
__global__ __launch_bounds__(512, 6) void dwconv_mfma(
    const float* __restrict__ x, const uint4* __restrict__ wB,
    const float* __restrict__ bf, float* __restrict__ out) {
    __shared__ __align__(16) unsigned lds[LROWS * LSTR32];
    __fp16* tile = (__fp16*)lds;

    const int t = threadIdx.x;               // 0..511
    const int img = blockIdx.x;              // n*384 + c
    const int c = __builtin_amdgcn_readfirstlane(img % 384);
    const size_t base = (size_t)img * 4096;

    // ---- issue staging global loads FIRST (8 f32 per thread) ----
    const int sr = t >> 3;                   // 0..63
    const int sq = t & 7;                    // 0..7
    const float4* srcp = (const float4*)(x + base + sr * 64 + sq * 8);
    const float4 xa = srcp[0];
    const float4 xb = srcp[1];

    // ---- zero halos (disjoint from interior writes; no barrier needed) ----
    // top rows 0..5 / bottom rows 70..75: 11 uint4 per row = 132 slots
    if (t < 132) {
        const int r = t / 11;
        const int rr = (r < 6) ? r : r + 64;
        const int qq = t - r * 11;
        *(uint4*)(lds + rr * LSTR32 + qq * 4) = make_uint4(0u, 0u, 0u, 0u);
    }
    // interior rows 6..69: left halo u32 0..3, right halo u32 36..43 (192 slots)
    if (t >= 320) {
        const int i = t - 320;
        const int r = 6 + i / 3;
        const int s = i % 3;
        const int sb = (s == 0) ? 0 : (s == 1 ? 36 : 40);
        *(uint4*)(lds + r * LSTR32 + sb) = make_uint4(0u, 0u, 0u, 0u);
    }

    // ---- stage interior: row R=sr+6, halves [8+8sq, 16+8sq) ----
    {
        const int R = sr + 6;
        unsigned u0 = h2_as_u32(__builtin_amdgcn_cvt_pkrtz(xa.x, xa.y));
        unsigned u1 = h2_as_u32(__builtin_amdgcn_cvt_pkrtz(xa.z, xa.w));
        unsigned u2 = h2_as_u32(__builtin_amdgcn_cvt_pkrtz(xb.x, xb.y));
        unsigned u3 = h2_as_u32(__builtin_amdgcn_cvt_pkrtz(xb.z, xb.w));
        *(uint4*)(lds + R * LSTR32 + 4 + sq * 4) = make_uint4(u0, u1, u2, u3);
    }

    // ---- per-block invariants: B-fragments (register-resident) + bias ----
    const int l = t & 63;
    const int wv = t >> 6;                   // 0..7
    const int ct = wv & 3;                   // col tile -> c0 = 16*ct
    const int rh = wv >> 2;                  // row half -> rows 32*rh..32*rh+31
    f16x8 Bf[13];
    {
        const uint4* wbp = wB + (size_t)c * 832 + l;
#pragma unroll
        for (int dy = 0; dy < 13; ++dy) {
            union { uint4 u; f16x8 h; } cv;
            cv.u = wbp[dy * 64];
            Bf[dy] = cv.h;
        }
    }
    const float bv = bf[c];

    __syncthreads();

    const int lrow = l & 15;
    const int kb = (l >> 4) * 8;
    const __fp16* abase = tile + (32 * rh + lrow) * LSTRH + 16 * ct + kb;

    f32x4 acc0 = {bv, bv, bv, bv};
    f32x4 acc1 = {bv, bv, bv, bv};

#pragma unroll
    for (int dy = 0; dy < 13; ++dy) {
        const f16x8 a0 = *(const f16x8*)(abase + (dy) * LSTRH);
        const f16x8 a1 = *(const f16x8*)(abase + (16 + dy) * LSTRH);
        acc0 = __builtin_amdgcn_mfma_f32_16x16x32_f16(a0, Bf[dy], acc0, 0, 0, 0);
        acc1 = __builtin_amdgcn_mfma_f32_16x16x32_f16(a1, Bf[dy], acc1, 0, 0, 0);
    }

    // C layout: col = 16*ct + (l&15), rows = 32*rh + {0,16} + 4*(l>>4) + q
    const int ocol = 16 * ct + (l & 15);
    const int orow = 32 * rh + 4 * (l >> 4);
    float* ob = out + base;
#pragma unroll
    for (int q = 0; q < 4; ++q) {
        ob[(orow + q) * 64 + ocol] = acc0[q];
        ob[(orow + 16 + q) * 64 + ocol] = acc1[q];
    }
}

// ---------------------------------------------------------------------------
extern "C" void kernel_launch(void* const* d_in, const int* in_sizes, int n_in,
                              void* d_out, int out_size, void* d_ws,
                              size_t ws_size, hipStream_t stream) {
    const float* x = (const float*)d_in[0];
    const float* w_large = (const float*)d_in[1];
    const float* w_small = (const float*)d_in[2];
    const float* g_l = (const float*)d_in[3];
    const float* b_l = (const float*)d_in[4];
    const float* m_l = (const float*)d_in[5];
    const float* v_l = (const float*)d_in[6];
    const float* g_s = (const float*)d_in[7];
    const float* b_s = (const float*)d_in[8];
    const float* m_s = (const float*)d_in[9];
    const float* v_s = (const float*)d_in[10];
    const float* g_i = (const float*)d_in[11];
    const float* b_i = (const float*)d_in[12];
    const float* m_i = (const float*)d_in[13];
    const float* v_i = (const float*)d_in[14];
    float* outp = (float*)d_out;

    // ws layout: bf[384] f32 | wB[384*832] uint4 (5.11 MB)
    float* bfp = (float*)d_ws;
    uint4* wB = (uint4*)(bfp + 384);

    fuse_weights<<<384, 256, 0, stream>>>(w_large, w_small, g_l, b_l, m_l, v_l,
                                          g_s, b_s, m_s, v_s, g_i, b_i, m_i,
                                          v_i, bfp, wB);
    dwconv_mfma<<<16 * 384, 512, 0, stream>>>(x, wB, bfp, outp);
}

// Round 16
// 44.780 us; speedup vs baseline: 2.3887x; 1.0226x over previous
//
#include <hip/hip_runtime.h>

#define EPSV 1e-5f

typedef __fp16 f16x8 __attribute__((ext_vector_type(8)));
typedef float f32x4 __attribute__((ext_vector_type(4)));
typedef __fp16 half2v __attribute__((ext_vector_type(2)));

__device__ __forceinline__ unsigned h2_as_u32(half2v h) {
    union { half2v h; unsigned u; } cv;
    cv.h = h;
    return cv.u;
}

#define LROWS 76
#define WSTRU 20   // u32 per row of a wave-private region (40 halves)
#define WREGU (LROWS * WSTRU)   // 1520 u32 = 6080 B per wave

// ---------------------------------------------------------------------------
// Kernel 1: fold the 3 branches into one 13x13 kernel + bias; emit per-channel
// MFMA B-fragments: for each dy, 32x16 banded Toeplitz B_dy[k][i] = w[dy][k-i-2]
// in v_mfma_f32_16x16x32_f16 B-fragment order (lane l: i=l&15, k=8*(l>>4)+j).
// ---------------------------------------------------------------------------
__global__ __launch_bounds__(256) void fuse_weights(
    const float* __restrict__ w_large, const float* __restrict__ w_small,
    const float* __restrict__ g_l, const float* __restrict__ b_l,
    const float* __restrict__ m_l, const float* __restrict__ v_l,
    const float* __restrict__ g_s, const float* __restrict__ b_s,
    const float* __restrict__ m_s, const float* __restrict__ v_s,
    const float* __restrict__ g_i, const float* __restrict__ b_i,
    const float* __restrict__ m_i, const float* __restrict__ v_i,
    float* __restrict__ bf, uint4* __restrict__ wB) {
    __shared__ float sw[169];
    const int c = blockIdx.x;
    const int t = threadIdx.x;
    const float sl = g_l[c] * rsqrtf(v_l[c] + EPSV);
    const float ss = g_s[c] * rsqrtf(v_s[c] + EPSV);
    const float si = g_i[c] * rsqrtf(v_i[c] + EPSV);
    if (t < 169) {
        const int ky = t / 13, kx = t % 13;
        float w = w_large[c * 169 + t] * sl;
        if (ky >= 5 && ky <= 7 && kx >= 5 && kx <= 7)
            w += w_small[c * 9 + (ky - 5) * 3 + (kx - 5)] * ss;
        if (t == 6 * 13 + 6) w += si;
        sw[t] = w;
    }
    if (t == 0)
        bf[c] = (b_l[c] - m_l[c] * sl) + (b_s[c] - m_s[c] * ss) +
                (b_i[c] - m_i[c] * si);
    __syncthreads();
    for (int it = t; it < 832; it += 256) {   // 13 dy * 64 lanes
        const int dy = it >> 6;
        const int l = it & 63;
        const int i = l & 15;
        const int kb = (l >> 4) * 8;
        unsigned u[4];
#pragma unroll
        for (int jj = 0; jj < 4; ++jj) {
            const int kx0 = kb + 2 * jj - i - 2;
            const int kx1 = kx0 + 1;
            const float w0 =
                (kx0 >= 0 && kx0 <= 12) ? sw[dy * 13 + kx0] : 0.0f;
            const float w1 =
                (kx1 >= 0 && kx1 <= 12) ? sw[dy * 13 + kx1] : 0.0f;
            u[jj] = h2_as_u32(__builtin_amdgcn_cvt_pkrtz(w0, w1));
        }
        wB[(size_t)c * 832 + it] = make_uint4(u[0], u[1], u[2], u[3]);
    }
}

// ---------------------------------------------------------------------------
// Kernel 2: depthwise 13x13 + bias on matrix cores — BARRIER-FREE.
// One block (4 waves) per (n,c) image; each wave stages its OWN 76-row x
// 32-half A-window (cols [16wv, 16wv+32) of the padded image) into a private
// LDS region (row stride 40 halves, bank-even), then computes immediately:
// same-wave lgkmcnt ordering is the only sync needed. All halo chunks are
// fully-valid-or-fully-zero (8-aligned vs width 64) -> no partial masks.
// Per wave: 13 dy x {4 ds_read_b128 + 4 mfma_f32_16x16x32_f16}, Bf resident.
// ---------------------------------------------------------------------------
__global__ __launch_bounds__(256, 4) void dwconv_mfma(
    const float* __restrict__ x, const uint4* __restrict__ wB,
    const float* __restrict__ bf, float* __restrict__ out) {
    __shared__ __align__(16) unsigned lds[4 * WREGU];

    const int t = threadIdx.x;
    const int img = blockIdx.x;              // n*384 + c
    const int c = __builtin_amdgcn_readfirstlane(img % 384);
    const size_t base = (size_t)img * 4096;

    const int l = t & 63;
    const int wv = t >> 6;                   // wave id -> col tile c0 = 16*wv
    unsigned* __restrict__ wlds = lds + wv * WREGU;
    const int xc0 = 16 * wv - 8;             // x col of local chunk 0

    // ---- B-fragments + bias (global, L2-hot; independent of staging) ----
    const uint4* __restrict__ wbp = wB + (size_t)c * 832 + l;
    f16x8 Bf[13];
#pragma unroll
    for (int dy = 0; dy < 13; ++dy) {
        union { uint4 u; f16x8 h; } cv;
        cv.u = wbp[dy * 64];
        Bf[dy] = cv.h;
    }
    const float bv = bf[c];

    // ---- wave-private staging: 304 uint4 = 76 rows x 4 chunks ----
#pragma unroll
    for (int i = 0; i < 5; ++i) {
        const int idx = 64 * i + l;
        if (idx < 304) {
            const int row = idx >> 2;        // 0..75
            const int q = idx & 3;           // chunk (8 halves)
            const int xr = row - 6;
            const int xc = xc0 + 8 * q;
            uint4 val = make_uint4(0u, 0u, 0u, 0u);
            if (((unsigned)xr < 64u) && ((unsigned)xc < 64u)) {
                const float4* sp = (const float4*)(x + base + xr * 64 + xc);
                const float4 v0 = sp[0];
                const float4 v1 = sp[1];
                val.x = h2_as_u32(__builtin_amdgcn_cvt_pkrtz(v0.x, v0.y));
                val.y = h2_as_u32(__builtin_amdgcn_cvt_pkrtz(v0.z, v0.w));
                val.z = h2_as_u32(__builtin_amdgcn_cvt_pkrtz(v1.x, v1.y));
                val.w = h2_as_u32(__builtin_amdgcn_cvt_pkrtz(v1.z, v1.w));
            }
            *(uint4*)(wlds + row * WSTRU + q * 4) = val;
        }
    }
    // No __syncthreads: reads below are same-wave, ordered by lgkmcnt.

    // ---- compute: 4 row-tile accumulators, dy-inner, A from private LDS ----
    const int lrow = l & 15;
    const int g = l >> 4;                    // k-block -> local halves 8g
    const __fp16* abase = (const __fp16*)wlds + lrow * 40 + g * 8;

    f32x4 acc0 = {bv, bv, bv, bv};
    f32x4 acc1 = {bv, bv, bv, bv};
    f32x4 acc2 = {bv, bv, bv, bv};
    f32x4 acc3 = {bv, bv, bv, bv};

#pragma unroll
    for (int dy = 0; dy < 13; ++dy) {
        const f16x8 a0 = *(const f16x8*)(abase + (dy) * 40);
        const f16x8 a1 = *(const f16x8*)(abase + (16 + dy) * 40);
        const f16x8 a2 = *(const f16x8*)(abase + (32 + dy) * 40);
        const f16x8 a3 = *(const f16x8*)(abase + (48 + dy) * 40);
        acc0 = __builtin_amdgcn_mfma_f32_16x16x32_f16(a0, Bf[dy], acc0, 0, 0, 0);
        acc1 = __builtin_amdgcn_mfma_f32_16x16x32_f16(a1, Bf[dy], acc1, 0, 0, 0);
        acc2 = __builtin_amdgcn_mfma_f32_16x16x32_f16(a2, Bf[dy], acc2, 0, 0, 0);
        acc3 = __builtin_amdgcn_mfma_f32_16x16x32_f16(a3, Bf[dy], acc3, 0, 0, 0);
    }

    // C layout: col = 16*wv + (l&15), rows = 16*rt + 4*(l>>4) + q
    const int ocol = 16 * wv + (l & 15);
    const int orow = 4 * (l >> 4);
    float* ob = out + base;
#pragma unroll
    for (int q = 0; q < 4; ++q) {
        ob[(orow + q) * 64 + ocol] = acc0[q];
        ob[(16 + orow + q) * 64 + ocol] = acc1[q];
        ob[(32 + orow + q) * 64 + ocol] = acc2[q];
        ob[(48 + orow + q) * 64 + ocol] = acc3[q];
    }
}

// ---------------------------------------------------------------------------
extern "C" void kernel_launch(void* const* d_in, const int* in_sizes, int n_in,
                              void* d_out, int out_size, void* d_ws,
                              size_t ws_size, hipStream_t stream) {
    const float* x = (const float*)d_in[0];
    const float* w_large = (const float*)d_in[1];
    const float* w_small = (const float*)d_in[2];
    const float* g_l = (const float*)d_in[3];
    const float* b_l = (const float*)d_in[4];
    const float* m_l = (const float*)d_in[5];
    const float* v_l = (const float*)d_in[6];
    const float* g_s = (const float*)d_in[7];
    const float* b_s = (const float*)d_in[8];
    const float* m_s = (const float*)d_in[9];
    const float* v_s = (const float*)d_in[10];
    const float* g_i = (const float*)d_in[11];
    const float* b_i = (const float*)d_in[12];
    const float* m_i = (const float*)d_in[13];
    const float* v_i = (const float*)d_in[14];
    float* outp = (float*)d_out;

    // ws layout: bf[384] f32 | wB[384*832] uint4 (5.11 MB)
    float* bfp = (float*)d_ws;
    uint4* wB = (uint4*)(bfp + 384);

    fuse_weights<<<384, 256, 0, stream>>>(w_large, w_small, g_l, b_l, m_l, v_l,
                                          g_s, b_s, m_s, v_s, g_i, b_i, m_i,
                                          v_i, bfp, wB);
    dwconv_mfma<<<16 * 384, 256, 0, stream>>>(x, wB, bfp, outp);
}

// Round 17
// 41.952 us; speedup vs baseline: 2.5497x; 1.0674x over previous
//
#include <hip/hip_runtime.h>

#define EPSV 1e-5f

typedef __fp16 f16x8 __attribute__((ext_vector_type(8)));
typedef float f32x4 __attribute__((ext_vector_type(4)));
typedef __fp16 half2v __attribute__((ext_vector_type(2)));

__device__ __forceinline__ unsigned h2_as_u32(half2v h) {
    union { half2v h; unsigned u; } cv;
    cv.h = h;
    return cv.u;
}

#define LROWS 76
#define LSTRIDE 88  // halves; 176B rows, 16B-aligned; wave64 b128 = 8 dw/bank (HW min)

// ---------------------------------------------------------------------------
// Kernel 1: fold the 3 branches into one 13x13 kernel + bias, then emit the
// per-channel MFMA B-fragments: for each dy (13), the 32x16 banded Toeplitz
// B_dy[k][i] = w[dy][k-i-2] (0 <= k-i-2 <= 12, else 0), stored directly in
// v_mfma_f32_16x16x32_f16 B-fragment order: lane l holds i = l&15,
// k = 8*(l>>4)+j (j=0..7) as 4 u32 (f16 pairs). wB[c][dy][lane] = uint4.
// ---------------------------------------------------------------------------
__global__ __launch_bounds__(256) void fuse_weights(
    const float* __restrict__ w_large, const float* __restrict__ w_small,
    const float* __restrict__ g_l, const float* __restrict__ b_l,
    const float* __restrict__ m_l, const float* __restrict__ v_l,
    const float* __restrict__ g_s, const float* __restrict__ b_s,
    const float* __restrict__ m_s, const float* __restrict__ v_s,
    const float* __restrict__ g_i, const float* __restrict__ b_i,
    const float* __restrict__ m_i, const float* __restrict__ v_i,
    float* __restrict__ bf, uint4* __restrict__ wB) {
    __shared__ float sw[169];
    const int c = blockIdx.x;
    const int t = threadIdx.x;
    const float sl = g_l[c] * rsqrtf(v_l[c] + EPSV);
    const float ss = g_s[c] * rsqrtf(v_s[c] + EPSV);
    const float si = g_i[c] * rsqrtf(v_i[c] + EPSV);
    if (t < 169) {
        const int ky = t / 13, kx = t % 13;
        float w = w_large[c * 169 + t] * sl;
        if (ky >= 5 && ky <= 7 && kx >= 5 && kx <= 7)
            w += w_small[c * 9 + (ky - 5) * 3 + (kx - 5)] * ss;
        if (t == 6 * 13 + 6) w += si;
        sw[t] = w;
    }
    if (t == 0)
        bf[c] = (b_l[c] - m_l[c] * sl) + (b_s[c] - m_s[c] * ss) +
                (b_i[c] - m_i[c] * si);
    __syncthreads();
    // 13 dy * 64 lanes = 832 fragment items, 4 u32 each
    for (int it = t; it < 832; it += 256) {
        const int dy = it >> 6;
        const int l = it & 63;
        const int i = l & 15;
        const int kb = (l >> 4) * 8;
        unsigned u[4];
#pragma unroll
        for (int jj = 0; jj < 4; ++jj) {
            const int kx0 = kb + 2 * jj - i - 2;
            const int kx1 = kx0 + 1;
            const float w0 =
                (kx0 >= 0 && kx0 <= 12) ? sw[dy * 13 + kx0] : 0.0f;
            const float w1 =
                (kx1 >= 0 && kx1 <= 12) ? sw[dy * 13 + kx1] : 0.0f;
            u[jj] = h2_as_u32(__builtin_amdgcn_cvt_pkrtz(w0, w1));
        }
        wB[(size_t)c * 832 + it] = make_uint4(u[0], u[1], u[2], u[3]);
    }
}

// ---------------------------------------------------------------------------
// Kernel 2: depthwise 13x13 + bias on MATRIX CORES. One block (256 thr =
// 4 waves) per (n,c) image. Stage zero-padded f16 image in LDS (76 x 88
// halves). Wave wv owns output column tile c0=16*wv; iterates 4 row tiles.
// Per (row-tile, dy): one ds_read_b128 A-fragment (lane l: row l&15, halves
// c0 + 8*(l>>4)) + one v_mfma_f32_16x16x32_f16 with the precomputed
// B-fragment (13 held in VGPRs). C: col=lane&15, row=4*(lane>>4)+q.
// ---------------------------------------------------------------------------
__global__ __launch_bounds__(256, 4) void dwconv_mfma(
    const float* __restrict__ x, const uint4* __restrict__ wB,
    const float* __restrict__ bf, float* __restrict__ out) {
    __shared__ __align__(16) __fp16 tile[LROWS * LSTRIDE];

    const int t = threadIdx.x;
    const int img = blockIdx.x;  // n*384 + c
    const int c = __builtin_amdgcn_readfirstlane(img % 384);
    const size_t base = (size_t)img * 4096;

    // ---- zero the whole padded tile ----
    unsigned* tz = (unsigned*)tile;  // 76*44 = 3344 u32
    for (int i2 = t; i2 < LROWS * LSTRIDE / 2; i2 += 256) tz[i2] = 0u;
    __syncthreads();

    // ---- stage interior: row r = t>>2, 16 f32 at col (t&3)*16 ----
    {
        const int r = t >> 2;
        const int q = t & 3;
        const float* src = x + base + r * 64 + q * 16;
        unsigned u[8];
#pragma unroll
        for (int p = 0; p < 4; ++p) {
            const float4 v = ((const float4*)src)[p];
            u[2 * p + 0] = h2_as_u32(__builtin_amdgcn_cvt_pkrtz(v.x, v.y));
            u[2 * p + 1] = h2_as_u32(__builtin_amdgcn_cvt_pkrtz(v.z, v.w));
        }
        // dest halves: (r+6)*88 + 8 + q*16  -> u32 index (r+6)*44 + 4 + q*8
        unsigned* dst = tz + (r + 6) * 44 + 4 + q * 8;
        *(uint4*)dst = make_uint4(u[0], u[1], u[2], u[3]);
        *(uint4*)(dst + 4) = make_uint4(u[4], u[5], u[6], u[7]);
    }

    // ---- load the 13 B-fragments (wave-shared data, L1/L2 resident) ----
    const int l = t & 63;
    const int wv = t >> 6;  // wave id 0..3 -> c0 = 16*wv
    f16x8 Bf[13];
    {
        const uint4* wbp = wB + (size_t)c * 832 + l;
#pragma unroll
        for (int dy = 0; dy < 13; ++dy) {
            union { uint4 u; f16x8 h; } cv;
            cv.u = wbp[dy * 64];
            Bf[dy] = cv.h;
        }
    }
    const float bv = bf[c];
    __syncthreads();

    const int c0 = wv * 16;
    const int lrow = l & 15;
    const int kb = (l >> 4) * 8;
    const __fp16* abase = tile + lrow * LSTRIDE + c0 + kb;

    const int ocol = c0 + (l & 15);
    const int orow = 4 * (l >> 4);

#pragma unroll 1
    for (int rp = 0; rp < 2; ++rp) {
        const int r0a = rp * 32;
        const int r0b = rp * 32 + 16;
        f32x4 accA = {bv, bv, bv, bv};
        f32x4 accB = {bv, bv, bv, bv};
#pragma unroll
        for (int dy = 0; dy < 13; ++dy) {
            const f16x8 a0 = *(const f16x8*)(abase + (r0a + dy) * LSTRIDE);
            const f16x8 a1 = *(const f16x8*)(abase + (r0b + dy) * LSTRIDE);
            accA = __builtin_amdgcn_mfma_f32_16x16x32_f16(a0, Bf[dy], accA,
                                                          0, 0, 0);
            accB = __builtin_amdgcn_mfma_f32_16x16x32_f16(a1, Bf[dy], accB,
                                                          0, 0, 0);
        }
        float* ob = out + base;
#pragma unroll
        for (int q = 0; q < 4; ++q) {
            ob[(r0a + orow + q) * 64 + ocol] = accA[q];
            ob[(r0b + orow + q) * 64 + ocol] = accB[q];
        }
    }
}

// ---------------------------------------------------------------------------
extern "C" void kernel_launch(void* const* d_in, const int* in_sizes, int n_in,
                              void* d_out, int out_size, void* d_ws,
                              size_t ws_size, hipStream_t stream) {
    const float* x = (const float*)d_in[0];
    const float* w_large = (const float*)d_in[1];
    const float* w_small = (const float*)d_in[2];
    const float* g_l = (const float*)d_in[3];
    const float* b_l = (const float*)d_in[4];
    const float* m_l = (const float*)d_in[5];
    const float* v_l = (const float*)d_in[6];
    const float* g_s = (const float*)d_in[7];
    const float* b_s = (const float*)d_in[8];
    const float* m_s = (const float*)d_in[9];
    const float* v_s = (const float*)d_in[10];
    const float* g_i = (const float*)d_in[11];
    const float* b_i = (const float*)d_in[12];
    const float* m_i = (const float*)d_in[13];
    const float* v_i = (const float*)d_in[14];
    float* outp = (float*)d_out;

    // ws layout: bf[384] f32 | wB[384*832] uint4 (5.11 MB)
    float* bfp = (float*)d_ws;
    uint4* wB = (uint4*)(bfp + 384);

    fuse_weights<<<384, 256, 0, stream>>>(w_large, w_small, g_l, b_l, m_l, v_l,
                                          g_s, b_s, m_s, v_s, g_i, b_i, m_i,
                                          v_i, bfp, wB);
    dwconv_mfma<<<16 * 384, 256, 0, stream>>>(x, wB, bfp, outp);
}